// Round 1
// baseline (383.158 us; speedup 1.0000x reference)
//
#include <hip/hip_runtime.h>
#include <hip/hip_bf16.h>
#include <math.h>

#define DIM   768
#define BATCH 32
#define SEQ   2048
#define SCALE 0.036084391824351615f  // 1/sqrt(768)

__device__ __forceinline__ float wave_sum(float v) {
#pragma unroll
    for (int o = 32; o > 0; o >>= 1) v += __shfl_xor(v, o, 64);
    return v;
}
__device__ __forceinline__ float wave_max(float v) {
#pragma unroll
    for (int o = 32; o > 0; o >>= 1) v = fmaxf(v, __shfl_xor(v, o, 64));
    return v;
}

// ---------------------------------------------------------------------------
// Small GEMM: out[M x N] = A[M x K] @ W[K x N] + bias[N]
// grid = (N/64, M/32), block = 256. Optional step indirection for W/bias.
// ---------------------------------------------------------------------------
__global__ void gemm_small(const float* __restrict__ A, int lda,
                           const float* __restrict__ W,
                           const float* __restrict__ bias,
                           float* __restrict__ out, int ldo,
                           int K, int N,
                           const int* __restrict__ step_ptr,
                           int wstride, int bstride) {
    const float* Wp = W;
    const float* bp = bias;
    if (step_ptr) {
        int st = step_ptr[0];
        Wp += (long)st * wstride;
        bp += (long)st * bstride;
    }
    const int jt = blockIdx.x * 64;
    const int r0 = blockIdx.y * 32;
    __shared__ float As[32][33];
    __shared__ float Ws[32][64];
    const int t = threadIdx.x;
    const int j = t & 63;
    const int bg = t >> 6;  // wave id, 0..3
    float acc[8];
#pragma unroll
    for (int i = 0; i < 8; i++) acc[i] = 0.f;

    for (int k0 = 0; k0 < K; k0 += 32) {
        {   // A tile 32x32, float4 per thread
            int r  = t >> 3;
            int kk = (t & 7) * 4;
            float4 av = *(const float4*)(A + (long)(r0 + r) * lda + k0 + kk);
            As[r][kk] = av.x; As[r][kk + 1] = av.y; As[r][kk + 2] = av.z; As[r][kk + 3] = av.w;
        }
#pragma unroll
        for (int i = 0; i < 8; i++) {  // W tile 32x64
            int idx = t + i * 256;
            int kk = idx >> 6, jj = idx & 63;
            Ws[kk][jj] = Wp[(long)(k0 + kk) * N + jt + jj];
        }
        __syncthreads();
#pragma unroll 8
        for (int kk = 0; kk < 32; kk++) {
            float wv = Ws[kk][j];
#pragma unroll
            for (int i = 0; i < 8; i++) acc[i] += As[bg * 8 + i][kk] * wv;
        }
        __syncthreads();
    }
    float bv = bp[jt + j];
#pragma unroll
    for (int i = 0; i < 8; i++)
        out[(long)(r0 + bg * 8 + i) * ldo + jt + j] = acc[i] + bv;
}

// ---------------------------------------------------------------------------
// LayerNorm + ReLU over rows of 768. Optional elementwise *wattn fold.
// grid = M, block = 256 (3 elements/thread)
// ---------------------------------------------------------------------------
__global__ void ln_relu(const float* __restrict__ z,
                        const float* __restrict__ g, const float* __restrict__ b,
                        const float* __restrict__ wattn,
                        float* __restrict__ out) {
    const int row = blockIdx.x;
    const int t = threadIdx.x;
    __shared__ float r1[4], r2[4];
    const float* zr = z + (long)row * DIM;
    float x[3]; float s = 0.f, ss = 0.f;
#pragma unroll
    for (int i = 0; i < 3; i++) { x[i] = zr[t + i * 256]; s += x[i]; ss += x[i] * x[i]; }
    float ws_ = wave_sum(s), wss = wave_sum(ss);
    int lane = t & 63, wid = t >> 6;
    if (lane == 0) { r1[wid] = ws_; r2[wid] = wss; }
    __syncthreads();
    s  = r1[0] + r1[1] + r1[2] + r1[3];
    ss = r2[0] + r2[1] + r2[2] + r2[3];
    float mu = s * (1.f / DIM);
    float var = ss * (1.f / DIM) - mu * mu;
    float rs = rsqrtf(var + 1e-5f);
#pragma unroll
    for (int i = 0; i < 3; i++) {
        int jj = t + i * 256;
        float y = (x[i] - mu) * rs * g[jj] + b[jj];
        y = y > 0.f ? y : 0.f;
        if (wattn) y *= wattn[jj];
        out[(long)row * DIM + jj] = y;
    }
}

// Final dual-LN: rows 0..31 -> ln3 -> nc[b][0:768]; rows 32..63 -> ln4 -> nc[b][768:1536]
__global__ void ln_final(const float* __restrict__ z,
                         const float* __restrict__ g3, const float* __restrict__ b3,
                         const float* __restrict__ g4, const float* __restrict__ b4,
                         float* __restrict__ nc) {
    const int row = blockIdx.x;  // 0..63
    const int t = threadIdx.x;
    __shared__ float r1[4], r2[4];
    const float* zr = z + (long)row * DIM;
    float x[3]; float s = 0.f, ss = 0.f;
#pragma unroll
    for (int i = 0; i < 3; i++) { x[i] = zr[t + i * 256]; s += x[i]; ss += x[i] * x[i]; }
    float ws_ = wave_sum(s), wss = wave_sum(ss);
    int lane = t & 63, wid = t >> 6;
    if (lane == 0) { r1[wid] = ws_; r2[wid] = wss; }
    __syncthreads();
    s  = r1[0] + r1[1] + r1[2] + r1[3];
    ss = r2[0] + r2[1] + r2[2] + r2[3];
    float mu = s * (1.f / DIM);
    float var = ss * (1.f / DIM) - mu * mu;
    float rs = rsqrtf(var + 1e-5f);
    const float* g  = (row < 32) ? g3 : g4;
    const float* bb = (row < 32) ? b3 : b4;
    int bidx = row & 31;
    int off  = (row < 32) ? 0 : DIM;
#pragma unroll
    for (int i = 0; i < 3; i++) {
        int jj = t + i * 256;
        float y = (x[i] - mu) * rs * g[jj] + bb[jj];
        nc[(long)bidx * (2 * DIM) + off + jj] = y > 0.f ? y : 0.f;
    }
}

// concat [control | pa] -> A2 (32 x 2304)
__global__ void build_a2(const float* __restrict__ control,
                         const float* __restrict__ pa, float* __restrict__ A2) {
    int idx = blockIdx.x * 256 + threadIdx.x;  // < 32*2304
    int b = idx / 2304, k = idx - b * 2304;
    A2[idx] = (k < 2 * DIM) ? control[b * 2 * DIM + k] : pa[b * DIM + (k - 2 * DIM)];
}

// Logits: w[b,s] = (dot(context[b,s,:], u[b,:]) + b_attn) * SCALE
// grid = (SEQ/4, BATCH), block = 256 (4 waves, 1 row per wave)
__global__ void logits_kernel(const float* __restrict__ ctx, const float* __restrict__ u,
                              const float* __restrict__ b_attn, float* __restrict__ w) {
    const int b = blockIdx.y;
    const int t = threadIdx.x;
    __shared__ float us[DIM];
#pragma unroll
    for (int i = 0; i < 3; i++) us[t + i * 256] = u[b * DIM + t + i * 256];
    __syncthreads();
    const int wave = t >> 6, lane = t & 63;
    const int s = blockIdx.x * 4 + wave;
    const float4* crow = (const float4*)(ctx + ((long)b * SEQ + s) * DIM);
    float acc = 0.f;
#pragma unroll
    for (int i = 0; i < 3; i++) {
        float4 c  = crow[lane + i * 64];
        float4 uu = *(const float4*)(us + (lane + i * 64) * 4);
        acc += c.x * uu.x + c.y * uu.y + c.z * uu.z + c.w * uu.w;
    }
    acc = wave_sum(acc);
    if (lane == 0) w[(long)b * SEQ + s] = (acc + b_attn[0]) * SCALE;
}

// Per-b softmax stats for 3 masks: mz[b][0..2]=max, mz[b][3..5]=sumexp
// grid = BATCH, block = 256
__global__ void stats_kernel(const float* __restrict__ w, const float* __restrict__ qm1,
                             const float* __restrict__ qm2, float* __restrict__ mz) {
    const int b = blockIdx.x;
    const int t = threadIdx.x;
    __shared__ float red[3][4];
    float l[3][8];
    float m[3] = {-1e9f, -1e9f, -1e9f};
#pragma unroll
    for (int i = 0; i < 8; i++) {
        int s = t + i * 256;
        float wv = w[(long)b * SEQ + s];
        bool a1 = qm1[(long)b * SEQ + s] != 0.f;
        bool a2 = qm2[(long)b * SEQ + s] != 0.f;
        l[0][i] = (a1 || a2) ? wv : -1e9f;
        l[1][i] = a1 ? wv : -1e9f;
        l[2][i] = a2 ? wv : -1e9f;
        m[0] = fmaxf(m[0], l[0][i]); m[1] = fmaxf(m[1], l[1][i]); m[2] = fmaxf(m[2], l[2][i]);
    }
    int lane = t & 63, wid = t >> 6;
#pragma unroll
    for (int k = 0; k < 3; k++) {
        float v = wave_max(m[k]);
        if (lane == 0) red[k][wid] = v;
    }
    __syncthreads();
    float M[3];
#pragma unroll
    for (int k = 0; k < 3; k++)
        M[k] = fmaxf(fmaxf(red[k][0], red[k][1]), fmaxf(red[k][2], red[k][3]));
    __syncthreads();
    float zsum[3] = {0.f, 0.f, 0.f};
#pragma unroll
    for (int i = 0; i < 8; i++)
#pragma unroll
        for (int k = 0; k < 3; k++) zsum[k] += expf(l[k][i] - M[k]);
#pragma unroll
    for (int k = 0; k < 3; k++) {
        float v = wave_sum(zsum[k]);
        if (lane == 0) red[k][wid] = v;
    }
    __syncthreads();
    if (t == 0) {
#pragma unroll
        for (int k = 0; k < 3; k++) {
            mz[b * 6 + k]     = M[k];
            mz[b * 6 + 3 + k] = red[k][0] + red[k][1] + red[k][2] + red[k][3];
        }
    }
}

// Attention weights out + partial weighted context sums (deterministic, no atomics)
// grid = (SEQ/64, BATCH), block = 256. partial[chunk][b][k][768]
__global__ void attn_acc_kernel(const float* __restrict__ ctx, const float* __restrict__ w,
                                const float* __restrict__ qm1, const float* __restrict__ qm2,
                                const float* __restrict__ mz, float* __restrict__ attn_out,
                                float* __restrict__ partial) {
    const int b = blockIdx.y;
    const int chunk = blockIdx.x;
    const int s0 = chunk * 64;
    const int t = threadIdx.x;
    __shared__ float aw[3][64];
    if (t < 64) {
        int s = s0 + t;
        float wv = w[(long)b * SEQ + s];
        bool a1 = qm1[(long)b * SEQ + s] != 0.f;
        bool a2 = qm2[(long)b * SEQ + s] != 0.f;
        float l0 = (a1 || a2) ? wv : -1e9f;
        float l1 = a1 ? wv : -1e9f;
        float l2 = a2 ? wv : -1e9f;
        float a0v = expf(l0 - mz[b * 6 + 0]) / mz[b * 6 + 3];
        float a1v = expf(l1 - mz[b * 6 + 1]) / mz[b * 6 + 4];
        float a2v = expf(l2 - mz[b * 6 + 2]) / mz[b * 6 + 5];
        aw[0][t] = a0v; aw[1][t] = a1v; aw[2][t] = a2v;
        attn_out[((long)b * 3 + 0) * SEQ + s] = a0v;
        attn_out[((long)b * 3 + 1) * SEQ + s] = a1v;
        attn_out[((long)b * 3 + 2) * SEQ + s] = a2v;
    }
    __syncthreads();
    float acc[3][3];
#pragma unroll
    for (int k = 0; k < 3; k++)
#pragma unroll
        for (int i = 0; i < 3; i++) acc[k][i] = 0.f;

    for (int r = 0; r < 64; r++) {
        const float* crow = ctx + ((long)b * SEQ + s0 + r) * DIM;
        float c0 = crow[t], c1 = crow[t + 256], c2 = crow[t + 512];
        float w0 = aw[0][r], w1 = aw[1][r], w2 = aw[2][r];
        acc[0][0] += w0 * c0; acc[0][1] += w0 * c1; acc[0][2] += w0 * c2;
        acc[1][0] += w1 * c0; acc[1][1] += w1 * c1; acc[1][2] += w1 * c2;
        acc[2][0] += w2 * c0; acc[2][1] += w2 * c1; acc[2][2] += w2 * c2;
    }
    float* pb = partial + (((long)chunk * BATCH + b) * 3) * DIM;
#pragma unroll
    for (int k = 0; k < 3; k++)
#pragma unroll
        for (int i = 0; i < 3; i++)
            pb[k * DIM + t + i * 256] = acc[k][i];
}

// Reduce partials, l2-normalize, scatter into fused GEMM input A6 (64 x 1536)
// grid = (BATCH, 3): k=0 ncf, k=1 mc1, k=2 mc2
__global__ void norm_build(const float* __restrict__ partial, float* __restrict__ A6) {
    const int b = blockIdx.x, k = blockIdx.y;
    const int t = threadIdx.x;
    __shared__ float r1[4];
    float v[3] = {0.f, 0.f, 0.f};
    for (int c = 0; c < SEQ / 64; c++) {
        const float* p = partial + (((long)c * BATCH + b) * 3 + k) * DIM;
#pragma unroll
        for (int i = 0; i < 3; i++) v[i] += p[t + i * 256];
    }
    float ss = v[0] * v[0] + v[1] * v[1] + v[2] * v[2];
    float wss = wave_sum(ss);
    int lane = t & 63, wid = t >> 6;
    if (lane == 0) r1[wid] = wss;
    __syncthreads();
    ss = r1[0] + r1[1] + r1[2] + r1[3];
    float inv = 1.f / fmaxf(sqrtf(ss), 1e-12f);
#pragma unroll
    for (int i = 0; i < 3; i++) {
        int jj = t + i * 256;
        float nv = v[i] * inv;
        if (k == 0) {
            A6[(long)b * (2 * DIM) + DIM + jj] = nv;
            A6[(long)(32 + b) * (2 * DIM) + DIM + jj] = nv;
        } else if (k == 1) {
            A6[(long)b * (2 * DIM) + jj] = nv;
        } else {
            A6[(long)(32 + b) * (2 * DIM) + jj] = nv;
        }
    }
}

extern "C" void kernel_launch(void* const* d_in, const int* in_sizes, int n_in,
                              void* d_out, int out_size, void* d_ws, size_t ws_size,
                              hipStream_t stream) {
    const int*   step     = (const int*)  d_in[0];
    const float* ctx      = (const float*)d_in[1];
    const float* question = (const float*)d_in[2];
    const float* control  = (const float*)d_in[3];
    const float* qm1      = (const float*)d_in[4];
    const float* qm2      = (const float*)d_in[5];
    const float* W_pos    = (const float*)d_in[8];
    const float* b_pos    = (const float*)d_in[9];
    const float* ln1_g    = (const float*)d_in[10];
    const float* ln1_b    = (const float*)d_in[11];
    const float* W_cq     = (const float*)d_in[12];
    const float* b_cq     = (const float*)d_in[13];
    const float* ln2_g    = (const float*)d_in[14];
    const float* ln2_b    = (const float*)d_in[15];
    const float* W_attn   = (const float*)d_in[16];
    const float* b_attn   = (const float*)d_in[17];
    const float* W_fuse   = (const float*)d_in[18];
    const float* b_fuse   = (const float*)d_in[19];
    const float* ln3_g    = (const float*)d_in[20];
    const float* ln3_b    = (const float*)d_in[21];
    const float* ln4_g    = (const float*)d_in[22];
    const float* ln4_b    = (const float*)d_in[23];

    float* ws   = (float*)d_ws;
    float* pa   = ws;            // 32*768      = 24576
    float* A2   = ws + 24576;    // 32*2304     = 73728
    float* z    = ws + 98304;    // 64*768      = 49152 (reused z1/z2/z3)
    float* u    = ws + 147456;   // 32*768      = 24576
    float* w    = ws + 172032;   // 32*2048     = 65536
    float* mz   = ws + 237568;   // 32*6        = 192
    float* A6   = ws + 237760;   // 64*1536     = 98304
    float* part = ws + 336064;   // 32*32*3*768 = 2359296

    float* nc_out   = (float*)d_out;
    float* attn_out = (float*)d_out + BATCH * 2 * DIM;

    // pa = ln_relu(question @ W_pos[step] + b_pos[step])
    gemm_small<<<dim3(DIM / 64, 1), 256, 0, stream>>>(
        question, DIM, W_pos, b_pos, z, DIM, DIM, DIM, step, DIM * DIM, DIM);
    ln_relu<<<BATCH, 256, 0, stream>>>(z, ln1_g, ln1_b, nullptr, pa);

    // cq -> u = relu(ln(...)) * W_attn
    build_a2<<<(BATCH * 3 * DIM) / 256, 256, 0, stream>>>(control, pa, A2);
    gemm_small<<<dim3(DIM / 64, 1), 256, 0, stream>>>(
        A2, 3 * DIM, W_cq, b_cq, z, DIM, 3 * DIM, DIM, nullptr, 0, 0);
    ln_relu<<<BATCH, 256, 0, stream>>>(z, ln2_g, ln2_b, W_attn, u);

    // logits over context (201 MB read)
    logits_kernel<<<dim3(SEQ / 4, BATCH), 256, 0, stream>>>(ctx, u, b_attn, w);

    // softmax stats for 3 masks
    stats_kernel<<<BATCH, 256, 0, stream>>>(w, qm1, qm2, mz);

    // attention outputs + partial weighted sums (second context read)
    attn_acc_kernel<<<dim3(SEQ / 64, BATCH), 256, 0, stream>>>(
        ctx, w, qm1, qm2, mz, attn_out, part);

    // l2norm + build fused input
    norm_build<<<dim3(BATCH, 3), 256, 0, stream>>>(part, A6);

    // fused GEMM (64 x 1536) @ (1536 x 768), then dual-LN -> next_control
    gemm_small<<<dim3(DIM / 64, 2), 256, 0, stream>>>(
        A6, 2 * DIM, W_fuse, b_fuse, z, DIM, 2 * DIM, DIM, nullptr, 0, 0);
    ln_final<<<2 * BATCH, 256, 0, stream>>>(z, ln3_g, ln3_b, ln4_g, ln4_b, nc_out);
}

// Round 2
// 169.731 us; speedup vs baseline: 2.2574x; 2.2574x over previous
//
#include <hip/hip_runtime.h>
#include <hip/hip_bf16.h>
#include <math.h>

#define DIM   768
#define BATCH 32
#define SEQ   2048
#define SCALE 0.036084391824351615f  // 1/sqrt(768)

__device__ __forceinline__ float wave_sum(float v) {
#pragma unroll
    for (int o = 32; o > 0; o >>= 1) v += __shfl_xor(v, o, 64);
    return v;
}
__device__ __forceinline__ float wave_max(float v) {
#pragma unroll
    for (int o = 32; o > 0; o >>= 1) v = fmaxf(v, __shfl_xor(v, o, 64));
    return v;
}

// ---------------------------------------------------------------------------
// Split-K partial GEMM: part[kc][Mtot][768] += A[M x K-chunk] @ W[K-chunk x 768]
// grid = (768/64, Mtot/32, K/64), block = 256. No bias (folded into reduce).
// ---------------------------------------------------------------------------
__global__ void gemm_partial(const float* __restrict__ A, int lda,
                             const float* __restrict__ W,
                             float* __restrict__ part, int Mtot,
                             const int* __restrict__ step_ptr, int wstride) {
    const float* Wp = W + (step_ptr ? (long)step_ptr[0] * wstride : 0);
    const int jt = blockIdx.x * 64;
    const int r0 = blockIdx.y * 32;
    const int kc = blockIdx.z;
    __shared__ float As[32][33];
    __shared__ float Ws[32][64];
    const int t = threadIdx.x;
    const int j = t & 63;
    const int bg = t >> 6;
    float acc[8];
#pragma unroll
    for (int i = 0; i < 8; i++) acc[i] = 0.f;

    for (int k0 = kc * 64; k0 < kc * 64 + 64; k0 += 32) {
        {
            int r  = t >> 3;
            int kk = (t & 7) * 4;
            float4 av = *(const float4*)(A + (long)(r0 + r) * lda + k0 + kk);
            As[r][kk] = av.x; As[r][kk + 1] = av.y; As[r][kk + 2] = av.z; As[r][kk + 3] = av.w;
        }
#pragma unroll
        for (int i = 0; i < 8; i++) {
            int idx = t + i * 256;
            int kk = idx >> 6, jj = idx & 63;
            Ws[kk][jj] = Wp[(long)(k0 + kk) * DIM + jt + jj];
        }
        __syncthreads();
#pragma unroll 8
        for (int kk = 0; kk < 32; kk++) {
            float wv = Ws[kk][j];
#pragma unroll
            for (int i = 0; i < 8; i++) acc[i] += As[bg * 8 + i][kk] * wv;
        }
        __syncthreads();
    }
#pragma unroll
    for (int i = 0; i < 8; i++)
        part[((long)(kc * Mtot + r0 + bg * 8 + i)) * DIM + jt + j] = acc[i];
}

// ---------------------------------------------------------------------------
// Reduce split-K partials + bias, then LayerNorm+ReLU (+optional *wattn fold).
// grid = Mtot, block = 256 (3 cols/thread). out[row*ostride + ocol + j]
// ---------------------------------------------------------------------------
__global__ void reduce_ln(const float* __restrict__ part, int KC, int Mtot,
                          const float* __restrict__ bias,
                          const int* __restrict__ step_ptr, int bstride,
                          const float* __restrict__ g, const float* __restrict__ b,
                          const float* __restrict__ wattn,
                          float* __restrict__ out, int ostride, int ocol) {
    const int row = blockIdx.x;
    const int t = threadIdx.x;
    const float* bp = bias + (step_ptr ? (long)step_ptr[0] * bstride : 0);
    __shared__ float r1[4], r2[4];
    float x[3];
    float s = 0.f, ss = 0.f;
#pragma unroll
    for (int i = 0; i < 3; i++) {
        int jj = t + i * 256;
        float v = bp[jj];
        for (int kc = 0; kc < KC; kc++)
            v += part[((long)(kc * Mtot + row)) * DIM + jj];
        x[i] = v; s += v; ss += v * v;
    }
    float wsv = wave_sum(s), wss = wave_sum(ss);
    int lane = t & 63, wid = t >> 6;
    if (lane == 0) { r1[wid] = wsv; r2[wid] = wss; }
    __syncthreads();
    s  = r1[0] + r1[1] + r1[2] + r1[3];
    ss = r2[0] + r2[1] + r2[2] + r2[3];
    float mu = s * (1.f / DIM);
    float var = ss * (1.f / DIM) - mu * mu;
    float rs = rsqrtf(var + 1e-5f);
#pragma unroll
    for (int i = 0; i < 3; i++) {
        int jj = t + i * 256;
        float y = (x[i] - mu) * rs * g[jj] + b[jj];
        y = y > 0.f ? y : 0.f;
        if (wattn) y *= wattn[jj];
        out[(long)row * ostride + ocol + jj] = y;
    }
}

// Final: reduce partials + bias, dual LN (rows<32 -> ln3 -> nc[:,0:768];
// rows>=32 -> ln4 -> nc[:,768:1536]), ReLU. grid = 64, block = 256.
__global__ void reduce_ln_final(const float* __restrict__ part, int KC,
                                const float* __restrict__ bias,
                                const float* __restrict__ g3, const float* __restrict__ b3,
                                const float* __restrict__ g4, const float* __restrict__ b4,
                                float* __restrict__ nc) {
    const int row = blockIdx.x;  // 0..63
    const int t = threadIdx.x;
    __shared__ float r1[4], r2[4];
    float x[3];
    float s = 0.f, ss = 0.f;
#pragma unroll
    for (int i = 0; i < 3; i++) {
        int jj = t + i * 256;
        float v = bias[jj];
        for (int kc = 0; kc < KC; kc++)
            v += part[((long)(kc * 64 + row)) * DIM + jj];
        x[i] = v; s += v; ss += v * v;
    }
    float wsv = wave_sum(s), wss = wave_sum(ss);
    int lane = t & 63, wid = t >> 6;
    if (lane == 0) { r1[wid] = wsv; r2[wid] = wss; }
    __syncthreads();
    s  = r1[0] + r1[1] + r1[2] + r1[3];
    ss = r2[0] + r2[1] + r2[2] + r2[3];
    float mu = s * (1.f / DIM);
    float var = ss * (1.f / DIM) - mu * mu;
    float rs = rsqrtf(var + 1e-5f);
    const float* g  = (row < 32) ? g3 : g4;
    const float* bb = (row < 32) ? b3 : b4;
    int bidx = row & 31;
    int off  = (row < 32) ? 0 : DIM;
#pragma unroll
    for (int i = 0; i < 3; i++) {
        int jj = t + i * 256;
        float y = (x[i] - mu) * rs * g[jj] + bb[jj];
        nc[(long)bidx * (2 * DIM) + off + jj] = y > 0.f ? y : 0.f;
    }
}

// control -> A2[:, 0:1536]
__global__ void copy_control(const float* __restrict__ control, float* __restrict__ A2) {
    int idx = blockIdx.x * 256 + threadIdx.x;  // < 32*1536
    int b = idx / 1536, k = idx - b * 1536;
    A2[(long)b * 2304 + k] = control[idx];
}

// ---------------------------------------------------------------------------
// Fused attention pass: logits + per-chunk softmax stats + weighted partial
// sums (unnormalized; softmax denominator cancels under the later l2norm).
// grid = (SEQ/64, BATCH), block = 256.
// stat[(b*32+c)*6] = {m0,m1,m2,z0,z1,z2}; pvec[(b*32+c)*3+k][768]
// ---------------------------------------------------------------------------
__global__ void attn_fused(const float* __restrict__ ctx, const float* __restrict__ u,
                           const float* __restrict__ b_attn,
                           const float* __restrict__ qm1, const float* __restrict__ qm2,
                           float* __restrict__ w, float* __restrict__ stat,
                           float* __restrict__ pvec) {
    const int c = blockIdx.x;
    const int b = blockIdx.y;
    const int t = threadIdx.x;
    const int wave = t >> 6, lane = t & 63;
    __shared__ float us[DIM];
    __shared__ float lg[64];
    __shared__ float ew[3][64];
#pragma unroll
    for (int i = 0; i < 3; i++) us[t + i * 256] = u[b * DIM + t + i * 256];
    __syncthreads();
    const float batt = b_attn[0];
    const long rowbase = (long)b * SEQ + c * 64;
#pragma unroll 4
    for (int ii = 0; ii < 16; ii++) {
        int r = wave * 16 + ii;
        const float4* crow = (const float4*)(ctx + (rowbase + r) * DIM);
        float acc = 0.f;
#pragma unroll
        for (int i = 0; i < 3; i++) {
            float4 cv = crow[lane + i * 64];
            float4 uu = *(const float4*)(us + (lane + i * 64) * 4);
            acc += cv.x * uu.x + cv.y * uu.y + cv.z * uu.z + cv.w * uu.w;
        }
        acc = wave_sum(acc);
        if (lane == 0) {
            float lw = (acc + batt) * SCALE;
            lg[r] = lw;
            w[rowbase + r] = lw;
        }
    }
    __syncthreads();
    if (wave == 0) {
        float wv = lg[lane];
        bool a1 = qm1[rowbase + lane] != 0.f;
        bool a2 = qm2[rowbase + lane] != 0.f;
        float l0 = (a1 || a2) ? wv : -1e9f;
        float l1 = a1 ? wv : -1e9f;
        float l2 = a2 ? wv : -1e9f;
        float m0 = wave_max(l0), m1 = wave_max(l1), m2 = wave_max(l2);
        float e0 = expf(l0 - m0), e1 = expf(l1 - m1), e2 = expf(l2 - m2);
        ew[0][lane] = e0; ew[1][lane] = e1; ew[2][lane] = e2;
        float z0 = wave_sum(e0), z1 = wave_sum(e1), z2 = wave_sum(e2);
        if (lane == 0) {
            long si = ((long)b * 32 + c) * 6;
            stat[si + 0] = m0; stat[si + 1] = m1; stat[si + 2] = m2;
            stat[si + 3] = z0; stat[si + 4] = z1; stat[si + 5] = z2;
        }
    }
    __syncthreads();
    float acc[3][3];
#pragma unroll
    for (int k = 0; k < 3; k++)
#pragma unroll
        for (int i = 0; i < 3; i++) acc[k][i] = 0.f;
    for (int r = 0; r < 64; r++) {
        const float* crow = ctx + (rowbase + r) * DIM;
        float c0 = crow[t], c1 = crow[t + 256], c2 = crow[t + 512];
        float w0 = ew[0][r], w1 = ew[1][r], w2 = ew[2][r];
        acc[0][0] += w0 * c0; acc[0][1] += w0 * c1; acc[0][2] += w0 * c2;
        acc[1][0] += w1 * c0; acc[1][1] += w1 * c1; acc[1][2] += w1 * c2;
        acc[2][0] += w2 * c0; acc[2][1] += w2 * c1; acc[2][2] += w2 * c2;
    }
    float* pb = pvec + ((long)(b * 32 + c) * 3) * DIM;
#pragma unroll
    for (int k = 0; k < 3; k++)
#pragma unroll
        for (int i = 0; i < 3; i++)
            pb[k * DIM + t + i * 256] = acc[k][i];
}

// Combine chunk partials with exp(m_loc - M) rescale, l2-normalize, build A6.
// Also writes global softmax stats mz[b*6+k]=M, mz[b*6+3+k]=z.
// grid = (BATCH, 3): k=0 ncf, k=1 mc1, k=2 mc2. block = 256.
__global__ void combine_norm(const float* __restrict__ stat, const float* __restrict__ pvec,
                             float* __restrict__ A6, float* __restrict__ mz) {
    const int b = blockIdx.x, k = blockIdx.y;
    const int t = threadIdx.x;
    __shared__ float r1[4];
    float M = -1e30f;
    for (int c = 0; c < 32; c++)
        M = fmaxf(M, stat[((long)b * 32 + c) * 6 + k]);
    float v[3] = {0.f, 0.f, 0.f};
    float z = 0.f;
    for (int c = 0; c < 32; c++) {
        long si = ((long)b * 32 + c) * 6;
        float sc = expf(stat[si + k] - M);
        z += stat[si + 3 + k] * sc;
        const float* p = pvec + ((long)(b * 32 + c) * 3 + k) * DIM;
#pragma unroll
        for (int i = 0; i < 3; i++) v[i] += p[t + i * 256] * sc;
    }
    float ss = v[0] * v[0] + v[1] * v[1] + v[2] * v[2];
    float wss = wave_sum(ss);
    int lane = t & 63, wid = t >> 6;
    if (lane == 0) r1[wid] = wss;
    __syncthreads();
    ss = r1[0] + r1[1] + r1[2] + r1[3];
    float inv = 1.f / fmaxf(sqrtf(ss), 1e-12f);
#pragma unroll
    for (int i = 0; i < 3; i++) {
        int jj = t + i * 256;
        float nv = v[i] * inv;
        if (k == 0) {
            A6[(long)b * (2 * DIM) + DIM + jj] = nv;
            A6[(long)(32 + b) * (2 * DIM) + DIM + jj] = nv;
        } else if (k == 1) {
            A6[(long)b * (2 * DIM) + jj] = nv;
        } else {
            A6[(long)(32 + b) * (2 * DIM) + jj] = nv;
        }
    }
    if (t == 0) { mz[b * 6 + k] = M; mz[b * 6 + 3 + k] = z; }
}

// attentions output from cached logits + global stats. grid = BATCH, block 256.
__global__ void attn_out_kernel(const float* __restrict__ w, const float* __restrict__ qm1,
                                const float* __restrict__ qm2, const float* __restrict__ mz,
                                float* __restrict__ attn_out) {
    const int b = blockIdx.x;
    const int t = threadIdx.x;
    float M0 = mz[b * 6 + 0], M1 = mz[b * 6 + 1], M2 = mz[b * 6 + 2];
    float iz0 = 1.f / mz[b * 6 + 3], iz1 = 1.f / mz[b * 6 + 4], iz2 = 1.f / mz[b * 6 + 5];
#pragma unroll
    for (int i = 0; i < 8; i++) {
        int s = t + i * 256;
        float wv = w[(long)b * SEQ + s];
        bool a1 = qm1[(long)b * SEQ + s] != 0.f;
        bool a2 = qm2[(long)b * SEQ + s] != 0.f;
        float l0 = (a1 || a2) ? wv : -1e9f;
        float l1 = a1 ? wv : -1e9f;
        float l2 = a2 ? wv : -1e9f;
        attn_out[((long)b * 3 + 0) * SEQ + s] = expf(l0 - M0) * iz0;
        attn_out[((long)b * 3 + 1) * SEQ + s] = expf(l1 - M1) * iz1;
        attn_out[((long)b * 3 + 2) * SEQ + s] = expf(l2 - M2) * iz2;
    }
}

extern "C" void kernel_launch(void* const* d_in, const int* in_sizes, int n_in,
                              void* d_out, int out_size, void* d_ws, size_t ws_size,
                              hipStream_t stream) {
    const int*   step     = (const int*)  d_in[0];
    const float* ctx      = (const float*)d_in[1];
    const float* question = (const float*)d_in[2];
    const float* control  = (const float*)d_in[3];
    const float* qm1      = (const float*)d_in[4];
    const float* qm2      = (const float*)d_in[5];
    const float* W_pos    = (const float*)d_in[8];
    const float* b_pos    = (const float*)d_in[9];
    const float* ln1_g    = (const float*)d_in[10];
    const float* ln1_b    = (const float*)d_in[11];
    const float* W_cq     = (const float*)d_in[12];
    const float* b_cq     = (const float*)d_in[13];
    const float* ln2_g    = (const float*)d_in[14];
    const float* ln2_b    = (const float*)d_in[15];
    const float* W_attn   = (const float*)d_in[16];
    const float* b_attn   = (const float*)d_in[17];
    const float* W_fuse   = (const float*)d_in[18];
    const float* b_fuse   = (const float*)d_in[19];
    const float* ln3_g    = (const float*)d_in[20];
    const float* ln3_b    = (const float*)d_in[21];
    const float* ln4_g    = (const float*)d_in[22];
    const float* ln4_b    = (const float*)d_in[23];

    float* ws   = (float*)d_ws;
    float* A2   = ws;             // 32*2304          = 73728
    float* u    = ws + 73728;     // 32*768           = 24576
    float* w    = ws + 98304;     // 32*2048          = 65536
    float* mz   = ws + 163840;    // 32*6             = 192
    float* stat = ws + 164032;    // 32*32*6          = 6144
    float* A6   = ws + 170176;    // 64*1536          = 98304
    float* big  = ws + 268480;    // max(36*32*768, 24*64*768, 32*32*3*768) = 2359296

    float* nc_out   = (float*)d_out;
    float* attn_out = (float*)d_out + BATCH * 2 * DIM;

    // control into A2[:, 0:1536] (pa lands in A2[:, 1536:2304] from reduce_ln)
    copy_control<<<(BATCH * 2 * DIM) / 256, 256, 0, stream>>>(control, A2);

    // pa = ln_relu(question @ W_pos[step] + b_pos[step]) -> A2[:, 1536:]
    gemm_partial<<<dim3(DIM / 64, 1, DIM / 64), 256, 0, stream>>>(
        question, DIM, W_pos, big, 32, step, DIM * DIM);
    reduce_ln<<<BATCH, 256, 0, stream>>>(big, DIM / 64, 32, b_pos, step, DIM,
                                         ln1_g, ln1_b, nullptr, A2, 3 * DIM, 2 * DIM);

    // u = relu(ln(A2 @ W_cq + b_cq)) * W_attn
    gemm_partial<<<dim3(DIM / 64, 1, (3 * DIM) / 64), 256, 0, stream>>>(
        A2, 3 * DIM, W_cq, big, 32, nullptr, 0);
    reduce_ln<<<BATCH, 256, 0, stream>>>(big, (3 * DIM) / 64, 32, b_cq, nullptr, 0,
                                         ln2_g, ln2_b, W_attn, u, DIM, 0);

    // fused logits + chunk-local softmax stats + weighted partial sums
    attn_fused<<<dim3(SEQ / 64, BATCH), 256, 0, stream>>>(
        ctx, u, b_attn, qm1, qm2, w, stat, big);

    // combine + l2norm -> A6; global softmax stats -> mz
    combine_norm<<<dim3(BATCH, 3), 256, 0, stream>>>(stat, big, A6, mz);

    // attentions output
    attn_out_kernel<<<BATCH, 256, 0, stream>>>(w, qm1, qm2, mz, attn_out);

    // fused GEMM + dual-LN -> next_control
    gemm_partial<<<dim3(DIM / 64, 2, (2 * DIM) / 64), 256, 0, stream>>>(
        A6, 2 * DIM, W_fuse, big, 64, nullptr, 0);
    reduce_ln_final<<<2 * BATCH, 256, 0, stream>>>(big, (2 * DIM) / 64, b_fuse,
                                                   ln3_g, ln3_b, ln4_g, ln4_b, nc_out);
}

// Round 3
// 98.109 us; speedup vs baseline: 3.9054x; 1.7300x over previous
//
#include <hip/hip_runtime.h>
#include <hip/hip_bf16.h>
#include <math.h>

#define DIM   768
#define BATCH 32
#define SEQ   2048
#define SCALE 0.036084391824351615f  // 1/sqrt(768)

__device__ __forceinline__ float wave_sum(float v) {
#pragma unroll
    for (int o = 32; o > 0; o >>= 1) v += __shfl_xor(v, o, 64);
    return v;
}

__device__ __forceinline__ void fma4(float4& a, float s, const float4& c) {
    a.x += s * c.x; a.y += s * c.y; a.z += s * c.z; a.w += s * c.w;
}

// ---------------------------------------------------------------------------
// Split-K partial GEMM with dual-source A (concat along K at ksplit):
// part[kc][Mtot][768] = A[M x 64-chunk] @ W[chunk x 768]
// grid = (768/64, Mtot/32, K/64), block = 256.
// ---------------------------------------------------------------------------
__global__ __launch_bounds__(256) void gemm_partial(
        const float* __restrict__ A0, int lda0,
        const float* __restrict__ A1, int lda1, int ksplit,
        const float* __restrict__ W,
        float* __restrict__ part, int Mtot,
        const int* __restrict__ step_ptr, int wstride) {
    const float* Wp = W + (step_ptr ? (long)step_ptr[0] * wstride : 0);
    const int jt = blockIdx.x * 64;
    const int r0 = blockIdx.y * 32;
    const int kc = blockIdx.z;
    __shared__ float As[32][33];
    __shared__ float Ws[32][64];
    const int t = threadIdx.x;
    const int j = t & 63;
    const int bg = t >> 6;
    float acc[8];
#pragma unroll
    for (int i = 0; i < 8; i++) acc[i] = 0.f;

    for (int k0 = kc * 64; k0 < kc * 64 + 64; k0 += 32) {
        {   // A tile 32x32
            int r  = t >> 3;
            int kk = (t & 7) * 4;
            int ka = k0 + kk;
            float4 av;
            if (ka < ksplit)
                av = *(const float4*)(A0 + (long)(r0 + r) * lda0 + ka);
            else
                av = *(const float4*)(A1 + (long)(r0 + r) * lda1 + (ka - ksplit));
            As[r][kk] = av.x; As[r][kk + 1] = av.y; As[r][kk + 2] = av.z; As[r][kk + 3] = av.w;
        }
#pragma unroll
        for (int i = 0; i < 2; i++) {  // W tile 32x64, float4 loads
            int idx = t + i * 256;
            int row = idx >> 4, col4 = idx & 15;
            float4 wv = *(const float4*)(Wp + (long)(k0 + row) * DIM + jt + col4 * 4);
            *(float4*)&Ws[row][col4 * 4] = wv;
        }
        __syncthreads();
#pragma unroll 8
        for (int kk = 0; kk < 32; kk++) {
            float wv = Ws[kk][j];
#pragma unroll
            for (int i = 0; i < 8; i++) acc[i] += As[bg * 8 + i][kk] * wv;
        }
        __syncthreads();
    }
#pragma unroll
    for (int i = 0; i < 8; i++)
        part[((long)(kc * Mtot + r0 + bg * 8 + i)) * DIM + jt + j] = acc[i];
}

// ---------------------------------------------------------------------------
// Reduce split-K partials + bias, LayerNorm+ReLU (+optional *wattn fold).
// grid = Mtot, block = 256.
// ---------------------------------------------------------------------------
__global__ __launch_bounds__(256) void reduce_ln(
        const float* __restrict__ part, int KC, int Mtot,
        const float* __restrict__ bias,
        const int* __restrict__ step_ptr, int bstride,
        const float* __restrict__ g, const float* __restrict__ b,
        const float* __restrict__ wattn,
        float* __restrict__ out) {
    const int row = blockIdx.x;
    const int t = threadIdx.x;
    const float* bp = bias + (step_ptr ? (long)step_ptr[0] * bstride : 0);
    __shared__ float r1[4], r2[4];
    float x[3];
    float s = 0.f, ss = 0.f;
#pragma unroll
    for (int i = 0; i < 3; i++) {
        int jj = t + i * 256;
        float v = bp[jj];
#pragma unroll 4
        for (int kc = 0; kc < KC; kc++)
            v += part[((long)(kc * Mtot + row)) * DIM + jj];
        x[i] = v; s += v; ss += v * v;
    }
    float wsv = wave_sum(s), wss = wave_sum(ss);
    int lane = t & 63, wid = t >> 6;
    if (lane == 0) { r1[wid] = wsv; r2[wid] = wss; }
    __syncthreads();
    s  = r1[0] + r1[1] + r1[2] + r1[3];
    ss = r2[0] + r2[1] + r2[2] + r2[3];
    float mu = s * (1.f / DIM);
    float var = ss * (1.f / DIM) - mu * mu;
    float rs = rsqrtf(var + 1e-5f);
#pragma unroll
    for (int i = 0; i < 3; i++) {
        int jj = t + i * 256;
        float y = (x[i] - mu) * rs * g[jj] + b[jj];
        y = y > 0.f ? y : 0.f;
        if (wattn) y *= wattn[jj];
        out[(long)row * DIM + jj] = y;
    }
}

// Final: reduce + bias, dual LN, ReLU -> next_control. grid = 64, block 256.
__global__ __launch_bounds__(256) void reduce_ln_final(
        const float* __restrict__ part, int KC,
        const float* __restrict__ bias,
        const float* __restrict__ g3, const float* __restrict__ b3,
        const float* __restrict__ g4, const float* __restrict__ b4,
        float* __restrict__ nc) {
    const int row = blockIdx.x;  // 0..63
    const int t = threadIdx.x;
    __shared__ float r1[4], r2[4];
    float x[3];
    float s = 0.f, ss = 0.f;
#pragma unroll
    for (int i = 0; i < 3; i++) {
        int jj = t + i * 256;
        float v = bias[jj];
#pragma unroll 4
        for (int kc = 0; kc < KC; kc++)
            v += part[((long)(kc * 64 + row)) * DIM + jj];
        x[i] = v; s += v; ss += v * v;
    }
    float wsv = wave_sum(s), wss = wave_sum(ss);
    int lane = t & 63, wid = t >> 6;
    if (lane == 0) { r1[wid] = wsv; r2[wid] = wss; }
    __syncthreads();
    s  = r1[0] + r1[1] + r1[2] + r1[3];
    ss = r2[0] + r2[1] + r2[2] + r2[3];
    float mu = s * (1.f / DIM);
    float var = ss * (1.f / DIM) - mu * mu;
    float rs = rsqrtf(var + 1e-5f);
    const float* g  = (row < 32) ? g3 : g4;
    const float* bb = (row < 32) ? b3 : b4;
    int bidx = row & 31;
    int off  = (row < 32) ? 0 : DIM;
#pragma unroll
    for (int i = 0; i < 3; i++) {
        int jj = t + i * 256;
        float y = (x[i] - mu) * rs * g[jj] + bb[jj];
        nc[(long)bidx * (2 * DIM) + off + jj] = y > 0.f ? y : 0.f;
    }
}

// ---------------------------------------------------------------------------
// Fused attention: single ctx read. Each wave keeps 4 rows in registers for
// both the logit dot and the weighted accumulate. Raw exp (logits are O(0.1),
// no max needed; masked rows get exactly 0, matching f32 exp(-1e9)==0).
// grid = (SEQ/64, BATCH), block = 256 (4 waves x 4 rows x 4 groups = 64 rows).
// Outputs: w[b][s] logits; zpart[(b*32+c)*4+wave][3]; pvec[(b*32+c)*3+k][768].
// ---------------------------------------------------------------------------
__global__ __launch_bounds__(256) void attn_main(
        const float* __restrict__ ctx, const float* __restrict__ u,
        const float* __restrict__ b_attn,
        const float* __restrict__ qm1, const float* __restrict__ qm2,
        float* __restrict__ w, float* __restrict__ zpart,
        float* __restrict__ pvec) {
    const int c = blockIdx.x;
    const int b = blockIdx.y;
    const int t = threadIdx.x;
    const int wave = t >> 6, lane = t & 63;
    __shared__ float4 us4[192];
    __shared__ float4 red[4][3][192];
    if (t < 192) us4[t] = ((const float4*)(u + (long)b * DIM))[t];
    __syncthreads();
    const float batt = b_attn[0];
    const long row0 = (long)b * SEQ + c * 64;

    float4 acc[3][3];
#pragma unroll
    for (int k = 0; k < 3; k++)
#pragma unroll
        for (int i = 0; i < 3; i++) acc[k][i] = make_float4(0.f, 0.f, 0.f, 0.f);
    float zacc[3] = {0.f, 0.f, 0.f};

#pragma unroll 1
    for (int g = 0; g < 4; g++) {
        const int rw = g * 16 + wave * 4;
        float4 cr[4][3];
        float d[4];
#pragma unroll
        for (int rr = 0; rr < 4; rr++) {
            const float4* crow = (const float4*)(ctx + (row0 + rw + rr) * DIM);
            float dd = 0.f;
#pragma unroll
            for (int i = 0; i < 3; i++) {
                float4 cv = crow[lane + i * 64];
                cr[rr][i] = cv;
                float4 uu = us4[lane + i * 64];
                dd += cv.x * uu.x + cv.y * uu.y + cv.z * uu.z + cv.w * uu.w;
            }
            d[rr] = wave_sum(dd);
        }
        float lw0 = (d[0] + batt) * SCALE;
        float lw1 = (d[1] + batt) * SCALE;
        float lw2 = (d[2] + batt) * SCALE;
        float lw3 = (d[3] + batt) * SCALE;
        if (lane < 4) {
            float v = lane == 0 ? lw0 : lane == 1 ? lw1 : lane == 2 ? lw2 : lw3;
            w[row0 + rw + lane] = v;
        }
        // masks for the 4 rows: lanes 0-3 load qm1, lanes 4-7 load qm2
        float mv = 0.f;
        if (lane < 4) mv = qm1[row0 + rw + lane];
        else if (lane < 8) mv = qm2[row0 + rw + lane - 4];
#pragma unroll
        for (int rr = 0; rr < 4; rr++) {
            float a1 = __shfl(mv, rr, 64);
            float a2 = __shfl(mv, rr + 4, 64);
            float lwr = rr == 0 ? lw0 : rr == 1 ? lw1 : rr == 2 ? lw2 : lw3;
            float ev = __expf(lwr);
            float e0 = (a1 != 0.f || a2 != 0.f) ? ev : 0.f;
            float e1 = (a1 != 0.f) ? ev : 0.f;
            float e2 = (a2 != 0.f) ? ev : 0.f;
            zacc[0] += e0; zacc[1] += e1; zacc[2] += e2;
#pragma unroll
            for (int i = 0; i < 3; i++) {
                fma4(acc[0][i], e0, cr[rr][i]);
                fma4(acc[1][i], e1, cr[rr][i]);
                fma4(acc[2][i], e2, cr[rr][i]);
            }
        }
    }
    if (lane == 0) {
        float* zp = zpart + ((long)(b * 32 + c) * 4 + wave) * 3;
        zp[0] = zacc[0]; zp[1] = zacc[1]; zp[2] = zacc[2];
    }
#pragma unroll
    for (int k = 0; k < 3; k++)
#pragma unroll
        for (int i = 0; i < 3; i++)
            red[wave][k][lane + i * 64] = acc[k][i];
    __syncthreads();
    for (int idx = t; idx < 576; idx += 256) {
        int k = idx / 192, col = idx - k * 192;
        float4 a = red[0][k][col], bb = red[1][k][col];
        float4 cc = red[2][k][col], dd = red[3][k][col];
        float4 s;
        s.x = a.x + bb.x + cc.x + dd.x;
        s.y = a.y + bb.y + cc.y + dd.y;
        s.z = a.z + bb.z + cc.z + dd.z;
        s.w = a.w + bb.w + cc.w + dd.w;
        ((float4*)pvec)[((long)(b * 32 + c) * 3 + k) * 192 + col] = s;
    }
}

// ---------------------------------------------------------------------------
// Combine chunk partials, l2-normalize -> A6; write attentions output.
// grid = (BATCH, 3): k=0 ncf, k=1 mc1, k=2 mc2. block = 256.
// ---------------------------------------------------------------------------
__global__ __launch_bounds__(256) void combine_norm(
        const float* __restrict__ zpart, const float* __restrict__ pvec,
        const float* __restrict__ w,
        const float* __restrict__ qm1, const float* __restrict__ qm2,
        float* __restrict__ A6, float* __restrict__ attn_out) {
    const int b = blockIdx.x, k = blockIdx.y;
    const int t = threadIdx.x;
    const int lane = t & 63, wid = t >> 6;
    __shared__ float r1[4], r2[4];
    // softmax denominator
    float z = 0.f;
    for (int j = t; j < 128; j += 256)
        z += zpart[((long)(b * 32 + (j >> 2)) * 4 + (j & 3)) * 3 + k];
    z = wave_sum(z);
    if (lane == 0) r1[wid] = z;
    __syncthreads();
    z = r1[0] + r1[1] + r1[2] + r1[3];
    // vector combine
    float v[3] = {0.f, 0.f, 0.f};
    for (int cch = 0; cch < 32; cch++) {
        const float* p = pvec + ((long)(b * 32 + cch) * 3 + k) * DIM;
#pragma unroll
        for (int i = 0; i < 3; i++) v[i] += p[t + i * 256];
    }
    float ss = v[0] * v[0] + v[1] * v[1] + v[2] * v[2];
    float wss = wave_sum(ss);
    if (lane == 0) r2[wid] = wss;
    __syncthreads();
    ss = r2[0] + r2[1] + r2[2] + r2[3];
    float inv = 1.f / fmaxf(sqrtf(ss), 1e-12f);
#pragma unroll
    for (int i = 0; i < 3; i++) {
        int jj = t + i * 256;
        float nv = v[i] * inv;
        if (k == 0) {
            A6[(long)b * (2 * DIM) + DIM + jj] = nv;
            A6[(long)(32 + b) * (2 * DIM) + DIM + jj] = nv;
        } else if (k == 1) {
            A6[(long)b * (2 * DIM) + jj] = nv;
        } else {
            A6[(long)(32 + b) * (2 * DIM) + jj] = nv;
        }
    }
    // attentions output for this (b, k)
    float iz = 1.f / z;
#pragma unroll
    for (int ii = 0; ii < 8; ii++) {
        int s = t + ii * 256;
        float wv = w[(long)b * SEQ + s];
        float m1 = qm1[(long)b * SEQ + s];
        float m2 = qm2[(long)b * SEQ + s];
        bool act = (k == 0) ? (m1 != 0.f || m2 != 0.f) : (k == 1) ? (m1 != 0.f) : (m2 != 0.f);
        attn_out[((long)b * 3 + k) * SEQ + s] = act ? __expf(wv) * iz : 0.f;
    }
}

extern "C" void kernel_launch(void* const* d_in, const int* in_sizes, int n_in,
                              void* d_out, int out_size, void* d_ws, size_t ws_size,
                              hipStream_t stream) {
    const int*   step     = (const int*)  d_in[0];
    const float* ctx      = (const float*)d_in[1];
    const float* question = (const float*)d_in[2];
    const float* control  = (const float*)d_in[3];
    const float* qm1      = (const float*)d_in[4];
    const float* qm2      = (const float*)d_in[5];
    const float* W_pos    = (const float*)d_in[8];
    const float* b_pos    = (const float*)d_in[9];
    const float* ln1_g    = (const float*)d_in[10];
    const float* ln1_b    = (const float*)d_in[11];
    const float* W_cq     = (const float*)d_in[12];
    const float* b_cq     = (const float*)d_in[13];
    const float* ln2_g    = (const float*)d_in[14];
    const float* ln2_b    = (const float*)d_in[15];
    const float* W_attn   = (const float*)d_in[16];
    const float* b_attn   = (const float*)d_in[17];
    const float* W_fuse   = (const float*)d_in[18];
    const float* b_fuse   = (const float*)d_in[19];
    const float* ln3_g    = (const float*)d_in[20];
    const float* ln3_b    = (const float*)d_in[21];
    const float* ln4_g    = (const float*)d_in[22];
    const float* ln4_b    = (const float*)d_in[23];

    float* ws    = (float*)d_ws;
    float* pa    = ws;             // 32*768   = 24576
    float* u     = ws + 24576;     // 32*768   = 24576
    float* w     = ws + 49152;     // 32*2048  = 65536
    float* zpart = ws + 114688;    // 1024*4*3 = 12288
    float* A6    = ws + 126976;    // 64*1536  = 98304
    float* big   = ws + 225280;    // shared: gemm partials (<=1179648) / pvec (2359296)

    float* nc_out   = (float*)d_out;
    float* attn_out = (float*)d_out + BATCH * 2 * DIM;

    // pa = ln_relu(question @ W_pos[step] + b_pos[step])
    gemm_partial<<<dim3(DIM / 64, 1, DIM / 64), 256, 0, stream>>>(
        question, DIM, question, DIM, 1 << 30, W_pos, big, 32, step, DIM * DIM);
    reduce_ln<<<BATCH, 256, 0, stream>>>(big, DIM / 64, 32, b_pos, step, DIM,
                                         ln1_g, ln1_b, nullptr, pa);

    // u = relu(ln([control | pa] @ W_cq + b_cq)) * W_attn   (dual-source A)
    gemm_partial<<<dim3(DIM / 64, 1, (3 * DIM) / 64), 256, 0, stream>>>(
        control, 2 * DIM, pa, DIM, 2 * DIM, W_cq, big, 32, nullptr, 0);
    reduce_ln<<<BATCH, 256, 0, stream>>>(big, (3 * DIM) / 64, 32, b_cq, nullptr, 0,
                                         ln2_g, ln2_b, W_attn, u);

    // fused single-read attention
    attn_main<<<dim3(SEQ / 64, BATCH), 256, 0, stream>>>(
        ctx, u, b_attn, qm1, qm2, w, zpart, big);

    // combine + l2norm -> A6; attentions output
    combine_norm<<<dim3(BATCH, 3), 256, 0, stream>>>(
        zpart, big, w, qm1, qm2, A6, attn_out);

    // fused GEMM + dual-LN -> next_control
    gemm_partial<<<dim3(DIM / 64, 2, (2 * DIM) / 64), 256, 0, stream>>>(
        A6, 2 * DIM, A6, 2 * DIM, 1 << 30, W_fuse, big, 64, nullptr, 0);
    reduce_ln_final<<<2 * BATCH, 256, 0, stream>>>(big, (2 * DIM) / 64, b_fuse,
                                                   ln3_g, ln3_b, ln4_g, ln4_b, nc_out);
}